// Round 1
// baseline (2993.258 us; speedup 1.0000x reference)
//
#include <hip/hip_runtime.h>

#define NN 100000
#define NE 1600000

// ---------------- degree count (float atomics, exact for counts < 2^24) ----
__global__ __launch_bounds__(256) void deg_kernel(const int* __restrict__ src,
                                                  const int* __restrict__ dst,
                                                  float* __restrict__ degO,
                                                  float* __restrict__ degI, int E) {
    int e = blockIdx.x * 256 + threadIdx.x;
    if (e < E) {
        unsafeAtomicAdd(&degO[src[e]], 1.0f);
        unsafeAtomicAdd(&degI[dst[e]], 1.0f);
    }
}

// ---------------- deg -> rsqrt(clip(deg,1)) in place ----------------------
__global__ __launch_bounds__(256) void norm_kernel(float* __restrict__ degO,
                                                   float* __restrict__ degI, int n) {
    int i = blockIdx.x * 256 + threadIdx.x;
    if (i < n) {
        degO[i] = rsqrtf(fmaxf(degO[i], 1.0f));
        degI[i] = rsqrtf(fmaxf(degI[i], 1.0f));
    }
}

// ---------------- edge aggregation: agg[dst] += x[src]*normO[src] ---------
// 32 lanes per edge, float4 per lane (128 floats / edge)
__global__ __launch_bounds__(256) void agg_kernel(const float* __restrict__ x,
                                                  const int* __restrict__ src,
                                                  const int* __restrict__ dst,
                                                  const float* __restrict__ normO,
                                                  float* __restrict__ agg, int E) {
    long long g = (long long)blockIdx.x * 256 + threadIdx.x;
    int e = (int)(g >> 5);
    int lane = (int)(g & 31);
    if (e >= E) return;
    int s = src[e];
    int d = dst[e];
    float ns = normO[s];
    float4 v = *reinterpret_cast<const float4*>(&x[(size_t)s * 128 + lane * 4]);
    float* o = &agg[(size_t)d * 128 + lane * 4];
    unsafeAtomicAdd(o + 0, v.x * ns);
    unsafeAtomicAdd(o + 1, v.y * ns);
    unsafeAtomicAdd(o + 2, v.z * ns);
    unsafeAtomicAdd(o + 3, v.w * ns);
}

// ---------------- C[n,128] = (A * rowscale?) @ W[128,128] + bias (+relu) --
// block: 256 threads, 64 rows x 128 cols tile; 8x4 register micro-tile.
__global__ __launch_bounds__(256) void gemm128(const float* __restrict__ A,
                                               const float* __restrict__ rowscale,
                                               const float* __restrict__ W,
                                               const float* __restrict__ bias,
                                               float* __restrict__ C, int n, int relu) {
    __shared__ float As[16][64];    // [k][row]  (transposed A tile)  4 KB
    __shared__ float Ws[16][128];   // [k][col]                        8 KB
    const int tid = threadIdx.x;
    const int tx = tid & 31;        // col group: cols tx*4 .. tx*4+3
    const int ty = tid >> 5;        // row group: rows ty*8 .. ty*8+7
    const int row0 = blockIdx.x * 64;
    const int arow = tid & 63;      // A-load row within tile
    const int akq = tid >> 6;       // A-load k quad (0..3)
    const int grow = row0 + arow;

    float rs = 1.0f;
    if (rowscale != nullptr && grow < n) rs = rowscale[grow];

    float acc[8][4] = {};

    for (int k0 = 0; k0 < 128; k0 += 16) {
        float4 av = make_float4(0.f, 0.f, 0.f, 0.f);
        if (grow < n)
            av = *reinterpret_cast<const float4*>(&A[(size_t)grow * 128 + k0 + akq * 4]);
        av.x *= rs; av.y *= rs; av.z *= rs; av.w *= rs;
        // W chunk: rows k0..k0+15, 2048 floats = 512 float4, 2 per thread
        const float4* Wg = reinterpret_cast<const float4*>(W + k0 * 128);
        float4 w0 = Wg[tid];
        float4 w1 = Wg[256 + tid];
        __syncthreads();
        As[akq * 4 + 0][arow] = av.x;
        As[akq * 4 + 1][arow] = av.y;
        As[akq * 4 + 2][arow] = av.z;
        As[akq * 4 + 3][arow] = av.w;
        reinterpret_cast<float4*>(&Ws[0][0])[tid] = w0;
        reinterpret_cast<float4*>(&Ws[0][0])[256 + tid] = w1;
        __syncthreads();
#pragma unroll
        for (int kk = 0; kk < 16; ++kk) {
            float4 w = *reinterpret_cast<const float4*>(&Ws[kk][tx * 4]);
            float4 aA = *reinterpret_cast<const float4*>(&As[kk][ty * 8]);
            float4 aB = *reinterpret_cast<const float4*>(&As[kk][ty * 8 + 4]);
            float a[8] = {aA.x, aA.y, aA.z, aA.w, aB.x, aB.y, aB.z, aB.w};
            float wv[4] = {w.x, w.y, w.z, w.w};
#pragma unroll
            for (int r = 0; r < 8; ++r)
#pragma unroll
                for (int c = 0; c < 4; ++c)
                    acc[r][c] = fmaf(a[r], wv[c], acc[r][c]);
        }
    }

    float4 bv = *reinterpret_cast<const float4*>(&bias[tx * 4]);
#pragma unroll
    for (int r = 0; r < 8; ++r) {
        int row = row0 + ty * 8 + r;
        if (row < n) {
            float4 o;
            o.x = acc[r][0] + bv.x;
            o.y = acc[r][1] + bv.y;
            o.z = acc[r][2] + bv.z;
            o.w = acc[r][3] + bv.w;
            if (relu) {
                o.x = fmaxf(o.x, 0.f); o.y = fmaxf(o.y, 0.f);
                o.z = fmaxf(o.z, 0.f); o.w = fmaxf(o.w, 0.f);
            }
            *reinterpret_cast<float4*>(&C[(size_t)row * 128 + tx * 4]) = o;
        }
    }
}

extern "C" void kernel_launch(void* const* d_in, const int* in_sizes, int n_in,
                              void* d_out, int out_size, void* d_ws, size_t ws_size,
                              hipStream_t stream) {
    const float* x  = (const float*)d_in[0];
    const int*  src = (const int*)d_in[1];
    const int*  dst = (const int*)d_in[2];
    const float* Wc = (const float*)d_in[3];
    const float* bc = (const float*)d_in[4];
    const float* W1 = (const float*)d_in[5];
    const float* b1 = (const float*)d_in[6];
    const float* W2 = (const float*)d_in[7];
    const float* b2 = (const float*)d_in[8];
    float* out = (float*)d_out;

    char* ws = (char*)d_ws;
    float* agg   = (float*)ws;                                   // NN*128 f32 = 51.2 MB
    float* normO = (float*)(ws + (size_t)NN * 128 * 4);          // NN f32
    float* normI = normO + NN;                                   // NN f32

    // zero agg + both degree buffers (contiguous)
    hipMemsetAsync(agg, 0, (size_t)NN * 128 * 4 + (size_t)2 * NN * 4, stream);

    deg_kernel<<<(NE + 255) / 256, 256, 0, stream>>>(src, dst, normO, normI, NE);
    norm_kernel<<<(NN + 255) / 256, 256, 0, stream>>>(normO, normI, NN);
    agg_kernel<<<(int)(((long long)NE * 32 + 255) / 256), 256, 0, stream>>>(
        x, src, dst, normO, agg, NE);

    int gblocks = (NN + 63) / 64;
    // h = relu(agg*normI @ Wc + bc)   -> d_out
    gemm128<<<gblocks, 256, 0, stream>>>(agg, normI, Wc, bc, out, NN, 1);
    // h = relu(h @ W1 + b1)           -> agg (reuse)
    gemm128<<<gblocks, 256, 0, stream>>>(out, nullptr, W1, b1, agg, NN, 1);
    // out = h @ W2 + b2               -> d_out
    gemm128<<<gblocks, 256, 0, stream>>>(agg, nullptr, W2, b2, out, NN, 0);
}

// Round 2
// 664.410 us; speedup vs baseline: 4.5051x; 4.5051x over previous
//
#include <hip/hip_runtime.h>

#define NN 100000
#define NE 1600000

// ---- zero helper not needed: hipMemsetAsync used on contiguous region ----

// ---------------- degree count (int atomics) ------------------------------
__global__ __launch_bounds__(256) void deg_kernel(const int* __restrict__ src,
                                                  const int* __restrict__ dst,
                                                  int* __restrict__ degO,
                                                  int* __restrict__ degI, int E) {
    int e = blockIdx.x * 256 + threadIdx.x;
    if (e < E) {
        atomicAdd(&degO[src[e]], 1);
        atomicAdd(&degI[dst[e]], 1);
    }
}

// ---------------- single-block exclusive scan of degI -> rowptr -----------
__global__ __launch_bounds__(1024) void scan_kernel(const int* __restrict__ deg,
                                                    int* __restrict__ rowptr) {
    __shared__ int part[1024];
    const int CH = 98;  // 1024*98 >= 100000
    int t = threadIdx.x;
    int lo = t * CH, hi = min(lo + CH, NN);
    int s = 0;
    for (int i = lo; i < hi; ++i) s += deg[i];
    part[t] = s;
    __syncthreads();
    for (int off = 1; off < 1024; off <<= 1) {
        int v = (t >= off) ? part[t - off] : 0;
        __syncthreads();
        part[t] += v;
        __syncthreads();
    }
    int run = (t > 0) ? part[t - 1] : 0;
    for (int i = lo; i < hi; ++i) { rowptr[i] = run; run += deg[i]; }
    if (t == 1023) rowptr[NN] = run;
}

// ---------------- norms from integer degrees ------------------------------
__global__ __launch_bounds__(256) void norm_kernel(const int* __restrict__ degO,
                                                   const int* __restrict__ degI,
                                                   float* __restrict__ normO,
                                                   float* __restrict__ normI, int n) {
    int i = blockIdx.x * 256 + threadIdx.x;
    if (i < n) {
        normO[i] = rsqrtf(fmaxf((float)degO[i], 1.0f));
        normI[i] = rsqrtf(fmaxf((float)degI[i], 1.0f));
    }
}

// ---------------- scatter edges into CSR buckets --------------------------
__global__ __launch_bounds__(256) void scatter_kernel(const int* __restrict__ src,
                                                      const int* __restrict__ dst,
                                                      const int* __restrict__ rowptr,
                                                      int* __restrict__ cursor,
                                                      int* __restrict__ csr_src, int E) {
    int e = blockIdx.x * 256 + threadIdx.x;
    if (e < E) {
        int d = dst[e];
        int pos = rowptr[d] + atomicAdd(&cursor[d], 1);
        csr_src[pos] = src[e];
    }
}

// ---------------- gather: agg[v] = normI[v] * sum_{u in N(v)} x[u]*normO[u]
// 32 lanes per node (float4 each), 8 nodes per 256-block
__global__ __launch_bounds__(256) void gather_kernel(const float* __restrict__ x,
                                                     const int* __restrict__ rowptr,
                                                     const int* __restrict__ csr_src,
                                                     const float* __restrict__ normO,
                                                     const float* __restrict__ normI,
                                                     float* __restrict__ agg) {
    int node = blockIdx.x * 8 + (threadIdx.x >> 5);
    int lane = threadIdx.x & 31;
    if (node >= NN) return;
    int beg = rowptr[node], end = rowptr[node + 1];
    float ax = 0.f, ay = 0.f, az = 0.f, aw = 0.f;
    for (int j = beg; j < end; ++j) {
        int s = csr_src[j];
        float ns = normO[s];
        float4 v = *reinterpret_cast<const float4*>(&x[(size_t)s * 128 + lane * 4]);
        ax = fmaf(v.x, ns, ax);
        ay = fmaf(v.y, ns, ay);
        az = fmaf(v.z, ns, az);
        aw = fmaf(v.w, ns, aw);
    }
    float ni = normI[node];
    float4 o = make_float4(ax * ni, ay * ni, az * ni, aw * ni);
    *reinterpret_cast<float4*>(&agg[(size_t)node * 128 + lane * 4]) = o;
}

// ---------------- C[n,128] = A @ W[128,128] + bias (+relu); C may == A ----
__global__ __launch_bounds__(256) void gemm128(const float* __restrict__ A,
                                               const float* __restrict__ W,
                                               const float* __restrict__ bias,
                                               float* __restrict__ C, int n, int relu) {
    __shared__ float As[16][64];    // [k][row]
    __shared__ float Ws[16][128];   // [k][col]
    const int tid = threadIdx.x;
    const int tx = tid & 31;
    const int ty = tid >> 5;
    const int row0 = blockIdx.x * 64;
    const int arow = tid & 63;
    const int akq = tid >> 6;
    const int grow = row0 + arow;

    float acc[8][4] = {};

    for (int k0 = 0; k0 < 128; k0 += 16) {
        float4 av = make_float4(0.f, 0.f, 0.f, 0.f);
        if (grow < n)
            av = *reinterpret_cast<const float4*>(&A[(size_t)grow * 128 + k0 + akq * 4]);
        const float4* Wg = reinterpret_cast<const float4*>(W + k0 * 128);
        float4 w0 = Wg[tid];
        float4 w1 = Wg[256 + tid];
        __syncthreads();
        As[akq * 4 + 0][arow] = av.x;
        As[akq * 4 + 1][arow] = av.y;
        As[akq * 4 + 2][arow] = av.z;
        As[akq * 4 + 3][arow] = av.w;
        reinterpret_cast<float4*>(&Ws[0][0])[tid] = w0;
        reinterpret_cast<float4*>(&Ws[0][0])[256 + tid] = w1;
        __syncthreads();
#pragma unroll
        for (int kk = 0; kk < 16; ++kk) {
            float4 w = *reinterpret_cast<const float4*>(&Ws[kk][tx * 4]);
            float4 aA = *reinterpret_cast<const float4*>(&As[kk][ty * 8]);
            float4 aB = *reinterpret_cast<const float4*>(&As[kk][ty * 8 + 4]);
            float a[8] = {aA.x, aA.y, aA.z, aA.w, aB.x, aB.y, aB.z, aB.w};
            float wv[4] = {w.x, w.y, w.z, w.w};
#pragma unroll
            for (int r = 0; r < 8; ++r)
#pragma unroll
                for (int c = 0; c < 4; ++c)
                    acc[r][c] = fmaf(a[r], wv[c], acc[r][c]);
        }
    }

    float4 bv = *reinterpret_cast<const float4*>(&bias[tx * 4]);
#pragma unroll
    for (int r = 0; r < 8; ++r) {
        int row = row0 + ty * 8 + r;
        if (row < n) {
            float4 o;
            o.x = acc[r][0] + bv.x;
            o.y = acc[r][1] + bv.y;
            o.z = acc[r][2] + bv.z;
            o.w = acc[r][3] + bv.w;
            if (relu) {
                o.x = fmaxf(o.x, 0.f); o.y = fmaxf(o.y, 0.f);
                o.z = fmaxf(o.z, 0.f); o.w = fmaxf(o.w, 0.f);
            }
            *reinterpret_cast<float4*>(&C[(size_t)row * 128 + tx * 4]) = o;
        }
    }
}

extern "C" void kernel_launch(void* const* d_in, const int* in_sizes, int n_in,
                              void* d_out, int out_size, void* d_ws, size_t ws_size,
                              hipStream_t stream) {
    const float* x  = (const float*)d_in[0];
    const int*  src = (const int*)d_in[1];
    const int*  dst = (const int*)d_in[2];
    const float* Wc = (const float*)d_in[3];
    const float* bc = (const float*)d_in[4];
    const float* W1 = (const float*)d_in[5];
    const float* b1 = (const float*)d_in[6];
    const float* W2 = (const float*)d_in[7];
    const float* b2 = (const float*)d_in[8];
    float* out = (float*)d_out;

    char* ws = (char*)d_ws;
    int*   degO    = (int*)ws;                       // NN
    int*   degI    = degO + NN;                      // NN
    int*   cursor  = degI + NN;                      // NN
    int*   rowptr  = cursor + NN;                    // NN+1
    float* normO   = (float*)(rowptr + NN + 1);      // NN
    float* normI   = normO + NN;                     // NN
    int*   csr_src = (int*)(normI + NN);             // NE

    // zero degO, degI, cursor (contiguous 3*NN ints)
    hipMemsetAsync(degO, 0, (size_t)3 * NN * sizeof(int), stream);

    deg_kernel<<<(NE + 255) / 256, 256, 0, stream>>>(src, dst, degO, degI, NE);
    scan_kernel<<<1, 1024, 0, stream>>>(degI, rowptr);
    norm_kernel<<<(NN + 255) / 256, 256, 0, stream>>>(degO, degI, normO, normI, NN);
    scatter_kernel<<<(NE + 255) / 256, 256, 0, stream>>>(src, dst, rowptr, cursor, csr_src, NE);

    // agg (with both norms folded) -> d_out
    gather_kernel<<<(NN + 7) / 8, 256, 0, stream>>>(x, rowptr, csr_src, normO, normI, out);

    int gblocks = (NN + 63) / 64;
    // three dense layers, all in-place on d_out (block rows are self-contained)
    gemm128<<<gblocks, 256, 0, stream>>>(out, Wc, bc, out, NN, 1);
    gemm128<<<gblocks, 256, 0, stream>>>(out, W1, b1, out, NN, 1);
    gemm128<<<gblocks, 256, 0, stream>>>(out, W2, b2, out, NN, 0);
}

// Round 3
// 530.795 us; speedup vs baseline: 5.6392x; 1.2517x over previous
//
#include <hip/hip_runtime.h>

#define NN 100000
#define NE 1600000
#define NB 391  // ceil(NN/256)

// ---------------- degree count (int atomics) ------------------------------
__global__ __launch_bounds__(256) void deg_kernel(const int* __restrict__ src,
                                                  const int* __restrict__ dst,
                                                  int* __restrict__ degO,
                                                  int* __restrict__ degI, int E) {
    int e = blockIdx.x * 256 + threadIdx.x;
    if (e < E) {
        atomicAdd(&degO[src[e]], 1);
        atomicAdd(&degI[dst[e]], 1);
    }
}

// ---------------- scan phase 1: per-block sums ----------------------------
__global__ __launch_bounds__(256) void psum_kernel(const int* __restrict__ deg,
                                                   int* __restrict__ bsum) {
    int t = threadIdx.x;
    int i = blockIdx.x * 256 + t;
    __shared__ int sm[256];
    sm[t] = (i < NN) ? deg[i] : 0;
    __syncthreads();
    for (int o = 128; o; o >>= 1) {
        if (t < o) sm[t] += sm[t + o];
        __syncthreads();
    }
    if (t == 0) bsum[blockIdx.x] = sm[0];
}

// ---------------- scan phase 2: exclusive scan of NB partials -------------
__global__ __launch_bounds__(512) void pscan_kernel(const int* __restrict__ bsum,
                                                    int* __restrict__ boff) {
    __shared__ int sm[512];
    int t = threadIdx.x;
    int v = (t < NB) ? bsum[t] : 0;
    sm[t] = v;
    __syncthreads();
    for (int o = 1; o < 512; o <<= 1) {
        int u = (t >= o) ? sm[t - o] : 0;
        __syncthreads();
        sm[t] += u;
        __syncthreads();
    }
    if (t < NB) boff[t] = sm[t] - v;
}

// ---------------- scan phase 3: local scan + offset -> rowptr -------------
__global__ __launch_bounds__(256) void pfinal_kernel(const int* __restrict__ deg,
                                                     const int* __restrict__ boff,
                                                     int* __restrict__ rowptr) {
    int t = threadIdx.x;
    int i = blockIdx.x * 256 + t;
    int v = (i < NN) ? deg[i] : 0;
    __shared__ int sm[256];
    sm[t] = v;
    __syncthreads();
    for (int o = 1; o < 256; o <<= 1) {
        int u = (t >= o) ? sm[t - o] : 0;
        __syncthreads();
        sm[t] += u;
        __syncthreads();
    }
    if (i < NN) {
        int base = boff[blockIdx.x];
        int incl = base + sm[t];
        rowptr[i] = incl - v;
        if (i == NN - 1) rowptr[NN] = incl;
    }
}

// ---------------- norms from integer degrees ------------------------------
__global__ __launch_bounds__(256) void norm_kernel(const int* __restrict__ degO,
                                                   const int* __restrict__ degI,
                                                   float* __restrict__ normO,
                                                   float* __restrict__ normI, int n) {
    int i = blockIdx.x * 256 + threadIdx.x;
    if (i < n) {
        normO[i] = rsqrtf(fmaxf((float)degO[i], 1.0f));
        normI[i] = rsqrtf(fmaxf((float)degI[i], 1.0f));
    }
}

// ---------------- scatter edges into CSR buckets --------------------------
__global__ __launch_bounds__(256) void scatter_kernel(const int* __restrict__ src,
                                                      const int* __restrict__ dst,
                                                      const int* __restrict__ rowptr,
                                                      int* __restrict__ cursor,
                                                      int* __restrict__ csr_src, int E) {
    int e = blockIdx.x * 256 + threadIdx.x;
    if (e < E) {
        int d = dst[e];
        int pos = rowptr[d] + atomicAdd(&cursor[d], 1);
        csr_src[pos] = src[e];
    }
}

// ---------------- gather: agg[v] = normI[v] * sum_{u in N(v)} x[u]*normO[u]
__global__ __launch_bounds__(256) void gather_kernel(const float* __restrict__ x,
                                                     const int* __restrict__ rowptr,
                                                     const int* __restrict__ csr_src,
                                                     const float* __restrict__ normO,
                                                     const float* __restrict__ normI,
                                                     float* __restrict__ agg) {
    int node = blockIdx.x * 8 + (threadIdx.x >> 5);
    int lane = threadIdx.x & 31;
    if (node >= NN) return;
    int beg = rowptr[node], end = rowptr[node + 1];
    float ax = 0.f, ay = 0.f, az = 0.f, aw = 0.f;
    for (int j = beg; j < end; ++j) {
        int s = csr_src[j];
        float ns = normO[s];
        float4 v = *reinterpret_cast<const float4*>(&x[(size_t)s * 128 + lane * 4]);
        ax = fmaf(v.x, ns, ax);
        ay = fmaf(v.y, ns, ay);
        az = fmaf(v.z, ns, az);
        aw = fmaf(v.w, ns, aw);
    }
    float ni = normI[node];
    float4 o = make_float4(ax * ni, ay * ni, az * ni, aw * ni);
    *reinterpret_cast<float4*>(&agg[(size_t)node * 128 + lane * 4]) = o;
}

// ---------------- fused 3-layer MLP, 64 rows per block, in-place ----------
// out[i,:] = relu(relu(A[i,:]@Wc+bc)@W1+b1)@W2+b2   (layer3 no relu)
__global__ __launch_bounds__(256) void mlp_kernel(const float* __restrict__ A,
                                                  const float* __restrict__ Wc,
                                                  const float* __restrict__ bc,
                                                  const float* __restrict__ W1,
                                                  const float* __restrict__ b1,
                                                  const float* __restrict__ W2,
                                                  const float* __restrict__ b2,
                                                  float* __restrict__ C, int n) {
    __shared__ float HS[64][132];   // [row][col], pitch 132 (16B-aligned, pad)
    __shared__ float Ws[16][128];   // [k][col]
    const int tid = threadIdx.x;
    const int tx = tid & 31;        // cols tx*4..+3
    const int ty = tid >> 5;        // rows ty*8..+7
    const int row0 = blockIdx.x * 64;

    // stage 64 rows of A into HS (coalesced: one row per 32-lane group)
    {
        int r = tid >> 5;
        int c4 = (tid & 31) * 4;
#pragma unroll
        for (int i = 0; i < 8; ++i) {
            int row = i * 8 + r;
            int grow = row0 + row;
            float4 v = make_float4(0.f, 0.f, 0.f, 0.f);
            if (grow < n)
                v = *reinterpret_cast<const float4*>(&A[(size_t)grow * 128 + c4]);
            *reinterpret_cast<float4*>(&HS[row][c4]) = v;
        }
    }

    const float* Wl[3] = {Wc, W1, W2};
    const float* bl[3] = {bc, b1, b2};

    for (int layer = 0; layer < 3; ++layer) {
        float acc[8][4] = {};
        const float* W = Wl[layer];
        for (int k0 = 0; k0 < 128; k0 += 16) {
            __syncthreads();   // HS/Ws ready-to-overwrite barrier
            const float4* Wg = reinterpret_cast<const float4*>(W + k0 * 128);
            reinterpret_cast<float4*>(&Ws[0][0])[tid] = Wg[tid];
            reinterpret_cast<float4*>(&Ws[0][0])[256 + tid] = Wg[256 + tid];
            __syncthreads();
#pragma unroll
            for (int kq = 0; kq < 4; ++kq) {
                float4 a[8];
#pragma unroll
                for (int r = 0; r < 8; ++r)
                    a[r] = *reinterpret_cast<const float4*>(&HS[ty * 8 + r][k0 + kq * 4]);
#pragma unroll
                for (int k2 = 0; k2 < 4; ++k2) {
                    float4 w = *reinterpret_cast<const float4*>(&Ws[kq * 4 + k2][tx * 4]);
                    float wv[4] = {w.x, w.y, w.z, w.w};
#pragma unroll
                    for (int r = 0; r < 8; ++r) {
                        float av = (k2 == 0) ? a[r].x : (k2 == 1) ? a[r].y
                                 : (k2 == 2) ? a[r].z : a[r].w;
#pragma unroll
                        for (int c = 0; c < 4; ++c)
                            acc[r][c] = fmaf(av, wv[c], acc[r][c]);
                    }
                }
            }
        }
        float4 bv = *reinterpret_cast<const float4*>(&bl[layer][tx * 4]);
        __syncthreads();   // all HS reads complete before overwrite
        if (layer < 2) {
#pragma unroll
            for (int r = 0; r < 8; ++r) {
                float4 o;
                o.x = fmaxf(acc[r][0] + bv.x, 0.f);
                o.y = fmaxf(acc[r][1] + bv.y, 0.f);
                o.z = fmaxf(acc[r][2] + bv.z, 0.f);
                o.w = fmaxf(acc[r][3] + bv.w, 0.f);
                *reinterpret_cast<float4*>(&HS[ty * 8 + r][tx * 4]) = o;
            }
        } else {
#pragma unroll
            for (int r = 0; r < 8; ++r) {
                int row = row0 + ty * 8 + r;
                if (row < n) {
                    float4 o;
                    o.x = acc[r][0] + bv.x;
                    o.y = acc[r][1] + bv.y;
                    o.z = acc[r][2] + bv.z;
                    o.w = acc[r][3] + bv.w;
                    *reinterpret_cast<float4*>(&C[(size_t)row * 128 + tx * 4]) = o;
                }
            }
        }
    }
}

extern "C" void kernel_launch(void* const* d_in, const int* in_sizes, int n_in,
                              void* d_out, int out_size, void* d_ws, size_t ws_size,
                              hipStream_t stream) {
    const float* x  = (const float*)d_in[0];
    const int*  src = (const int*)d_in[1];
    const int*  dst = (const int*)d_in[2];
    const float* Wc = (const float*)d_in[3];
    const float* bc = (const float*)d_in[4];
    const float* W1 = (const float*)d_in[5];
    const float* b1 = (const float*)d_in[6];
    const float* W2 = (const float*)d_in[7];
    const float* b2 = (const float*)d_in[8];
    float* out = (float*)d_out;

    char* ws = (char*)d_ws;
    int*   degO    = (int*)ws;                       // NN
    int*   degI    = degO + NN;                      // NN
    int*   cursor  = degI + NN;                      // NN
    int*   rowptr  = cursor + NN;                    // NN+1
    float* normO   = (float*)(rowptr + NN + 1);      // NN
    float* normI   = normO + NN;                     // NN
    int*   bsum    = (int*)(normI + NN);             // NB
    int*   boff    = bsum + NB;                      // NB
    int*   csr_src = boff + NB;                      // NE

    // zero degO, degI, cursor (contiguous 3*NN ints)
    hipMemsetAsync(degO, 0, (size_t)3 * NN * sizeof(int), stream);

    deg_kernel<<<(NE + 255) / 256, 256, 0, stream>>>(src, dst, degO, degI, NE);
    psum_kernel<<<NB, 256, 0, stream>>>(degI, bsum);
    pscan_kernel<<<1, 512, 0, stream>>>(bsum, boff);
    pfinal_kernel<<<NB, 256, 0, stream>>>(degI, boff, rowptr);
    norm_kernel<<<(NN + 255) / 256, 256, 0, stream>>>(degO, degI, normO, normI, NN);
    scatter_kernel<<<(NE + 255) / 256, 256, 0, stream>>>(src, dst, rowptr, cursor, csr_src, NE);

    // agg (with both norms folded) -> d_out
    gather_kernel<<<(NN + 7) / 8, 256, 0, stream>>>(x, rowptr, csr_src, normO, normI, out);

    // fused 3-layer MLP, in-place on d_out
    mlp_kernel<<<(NN + 63) / 64, 256, 0, stream>>>(out, Wc, bc, W1, b1, W2, b2, out, NN);
}

// Round 4
// 446.961 us; speedup vs baseline: 6.6969x; 1.1876x over previous
//
#include <hip/hip_runtime.h>

#define NN 100000
#define NE 1600000
#define NB 391  // ceil(NN/256)

typedef __attribute__((ext_vector_type(8))) __bf16 bf16x8;
typedef __attribute__((ext_vector_type(4))) float f32x4;

// ---------------- degree count (int atomics) ------------------------------
__global__ __launch_bounds__(256) void deg_kernel(const int* __restrict__ src,
                                                  const int* __restrict__ dst,
                                                  int* __restrict__ degO,
                                                  int* __restrict__ degI, int E) {
    int e = blockIdx.x * 256 + threadIdx.x;
    if (e < E) {
        atomicAdd(&degO[src[e]], 1);
        atomicAdd(&degI[dst[e]], 1);
    }
}

// ---------------- scan phase 1: per-block sums ----------------------------
__global__ __launch_bounds__(256) void psum_kernel(const int* __restrict__ deg,
                                                   int* __restrict__ bsum) {
    int t = threadIdx.x;
    int i = blockIdx.x * 256 + t;
    __shared__ int sm[256];
    sm[t] = (i < NN) ? deg[i] : 0;
    __syncthreads();
    for (int o = 128; o; o >>= 1) {
        if (t < o) sm[t] += sm[t + o];
        __syncthreads();
    }
    if (t == 0) bsum[blockIdx.x] = sm[0];
}

// ---------------- scan phase 2: exclusive scan of NB partials -------------
__global__ __launch_bounds__(512) void pscan_kernel(const int* __restrict__ bsum,
                                                    int* __restrict__ boff) {
    __shared__ int sm[512];
    int t = threadIdx.x;
    int v = (t < NB) ? bsum[t] : 0;
    sm[t] = v;
    __syncthreads();
    for (int o = 1; o < 512; o <<= 1) {
        int u = (t >= o) ? sm[t - o] : 0;
        __syncthreads();
        sm[t] += u;
        __syncthreads();
    }
    if (t < NB) boff[t] = sm[t] - v;
}

// ---------------- scan phase 3: local scan + offset -> rowptr -------------
__global__ __launch_bounds__(256) void pfinal_kernel(const int* __restrict__ deg,
                                                     const int* __restrict__ boff,
                                                     int* __restrict__ rowptr) {
    int t = threadIdx.x;
    int i = blockIdx.x * 256 + t;
    int v = (i < NN) ? deg[i] : 0;
    __shared__ int sm[256];
    sm[t] = v;
    __syncthreads();
    for (int o = 1; o < 256; o <<= 1) {
        int u = (t >= o) ? sm[t - o] : 0;
        __syncthreads();
        sm[t] += u;
        __syncthreads();
    }
    if (i < NN) {
        int base = boff[blockIdx.x];
        int incl = base + sm[t];
        rowptr[i] = incl - v;
        if (i == NN - 1) rowptr[NN] = incl;
    }
}

// ---------------- norms from integer degrees ------------------------------
__global__ __launch_bounds__(256) void norm_kernel(const int* __restrict__ degO,
                                                   const int* __restrict__ degI,
                                                   float* __restrict__ normO,
                                                   float* __restrict__ normI, int n) {
    int i = blockIdx.x * 256 + threadIdx.x;
    if (i < n) {
        normO[i] = rsqrtf(fmaxf((float)degO[i], 1.0f));
        normI[i] = rsqrtf(fmaxf((float)degI[i], 1.0f));
    }
}

// ---------------- scatter edges into CSR buckets --------------------------
__global__ __launch_bounds__(256) void scatter_kernel(const int* __restrict__ src,
                                                      const int* __restrict__ dst,
                                                      const int* __restrict__ rowptr,
                                                      int* __restrict__ cursor,
                                                      int* __restrict__ csr_src, int E) {
    int e = blockIdx.x * 256 + threadIdx.x;
    if (e < E) {
        int d = dst[e];
        int pos = rowptr[d] + atomicAdd(&cursor[d], 1);
        csr_src[pos] = src[e];
    }
}

// ---------------- gather: agg[v] = normI[v] * sum_{u in N(v)} x[u]*normO[u]
__global__ __launch_bounds__(256) void gather_kernel(const float* __restrict__ x,
                                                     const int* __restrict__ rowptr,
                                                     const int* __restrict__ csr_src,
                                                     const float* __restrict__ normO,
                                                     const float* __restrict__ normI,
                                                     float* __restrict__ agg) {
    int node = blockIdx.x * 8 + (threadIdx.x >> 5);
    int lane = threadIdx.x & 31;
    if (node >= NN) return;
    int beg = rowptr[node], end = rowptr[node + 1];
    float ax = 0.f, ay = 0.f, az = 0.f, aw = 0.f;
    int j = beg;
    for (; j + 4 <= end; j += 4) {
        int s0 = csr_src[j], s1 = csr_src[j + 1], s2 = csr_src[j + 2], s3 = csr_src[j + 3];
        float n0 = normO[s0], n1 = normO[s1], n2 = normO[s2], n3 = normO[s3];
        float4 v0 = *reinterpret_cast<const float4*>(&x[(size_t)s0 * 128 + lane * 4]);
        float4 v1 = *reinterpret_cast<const float4*>(&x[(size_t)s1 * 128 + lane * 4]);
        float4 v2 = *reinterpret_cast<const float4*>(&x[(size_t)s2 * 128 + lane * 4]);
        float4 v3 = *reinterpret_cast<const float4*>(&x[(size_t)s3 * 128 + lane * 4]);
        ax = fmaf(v0.x, n0, ax); ay = fmaf(v0.y, n0, ay); az = fmaf(v0.z, n0, az); aw = fmaf(v0.w, n0, aw);
        ax = fmaf(v1.x, n1, ax); ay = fmaf(v1.y, n1, ay); az = fmaf(v1.z, n1, az); aw = fmaf(v1.w, n1, aw);
        ax = fmaf(v2.x, n2, ax); ay = fmaf(v2.y, n2, ay); az = fmaf(v2.z, n2, az); aw = fmaf(v2.w, n2, aw);
        ax = fmaf(v3.x, n3, ax); ay = fmaf(v3.y, n3, ay); az = fmaf(v3.z, n3, az); aw = fmaf(v3.w, n3, aw);
    }
    for (; j < end; ++j) {
        int s = csr_src[j];
        float ns = normO[s];
        float4 v = *reinterpret_cast<const float4*>(&x[(size_t)s * 128 + lane * 4]);
        ax = fmaf(v.x, ns, ax);
        ay = fmaf(v.y, ns, ay);
        az = fmaf(v.z, ns, az);
        aw = fmaf(v.w, ns, aw);
    }
    float ni = normI[node];
    float4 o = make_float4(ax * ni, ay * ni, az * ni, aw * ni);
    *reinterpret_cast<float4*>(&agg[(size_t)node * 128 + lane * 4]) = o;
}

// ---------------- W prep: pack Wc/W1/W2 into hi/lo bf16 B-fragments -------
// frag index f = (((layer*2+h)*4+kt)*8+ct)*64+lane ; elem j=0..7
// element: k = kt*32 + (lane>>4)*8 + j ; c = ct*16 + (lane&15) ; W[k*128+c]
__global__ __launch_bounds__(256) void wprep_kernel(const float* __restrict__ Wc,
                                                    const float* __restrict__ W1,
                                                    const float* __restrict__ W2,
                                                    __bf16* __restrict__ Wf) {
    int t = blockIdx.x * 256 + threadIdx.x;
    if (t >= 3 * 4 * 8 * 64) return;
    int lane = t & 63;
    int ct = (t >> 6) & 7;
    int kt = (t >> 9) & 3;
    int layer = t >> 11;
    const float* W = (layer == 0) ? Wc : (layer == 1) ? W1 : W2;
    int c = ct * 16 + (lane & 15);
    int kbase = kt * 32 + (lane >> 4) * 8;
    bf16x8 hi, lo;
#pragma unroll
    for (int j = 0; j < 8; ++j) {
        float wv = W[(size_t)(kbase + j) * 128 + c];
        __bf16 h = (__bf16)wv;
        hi[j] = h;
        lo[j] = (__bf16)(wv - (float)h);
    }
    bf16x8* Wv = reinterpret_cast<bf16x8*>(Wf);
    Wv[((size_t)((layer * 2 + 0) * 4 + kt) * 8 + ct) * 64 + lane] = hi;
    Wv[((size_t)((layer * 2 + 1) * 4 + kt) * 8 + ct) * 64 + lane] = lo;
}

// ---------------- fused 3-layer MLP via split-bf16 MFMA -------------------
// block: 256 thr = 4 waves; 64 rows; wave w owns rows [16w,16w+16)
__global__ __launch_bounds__(256) void mlp_mfma(const float* __restrict__ A,
                                                const __bf16* __restrict__ Wf,
                                                const float* __restrict__ bc,
                                                const float* __restrict__ b1,
                                                const float* __restrict__ b2,
                                                float* __restrict__ C, int n) {
    __shared__ float HS[64][132];
    const int tid = threadIdx.x;
    const int lane = tid & 63;
    const int wv = tid >> 6;          // wave 0..3
    const int row0 = blockIdx.x * 64;
    const int mrow = lane & 15;       // A-row within strip / C-col within tile
    const int kg = lane >> 4;         // 0..3

    // stage 64 rows of A
    {
        int r = tid >> 5;
        int c4 = (tid & 31) * 4;
#pragma unroll
        for (int i = 0; i < 8; ++i) {
            int row = i * 8 + r;
            int grow = row0 + row;
            float4 v = make_float4(0.f, 0.f, 0.f, 0.f);
            if (grow < n)
                v = *reinterpret_cast<const float4*>(&A[(size_t)grow * 128 + c4]);
            *reinterpret_cast<float4*>(&HS[row][c4]) = v;
        }
    }
    __syncthreads();

    const bf16x8* Wfrag = reinterpret_cast<const bf16x8*>(Wf);
    const float* bias[3] = {bc, b1, b2};

#pragma unroll
    for (int layer = 0; layer < 3; ++layer) {
        f32x4 acc[8] = {};
#pragma unroll
        for (int kt = 0; kt < 4; ++kt) {
            // A fragment: 8 consecutive f32 from this wave's strip
            const float* hsrc = &HS[wv * 16 + mrow][kt * 32 + kg * 8];
            float4 p0 = *reinterpret_cast<const float4*>(hsrc);
            float4 p1 = *reinterpret_cast<const float4*>(hsrc + 4);
            float av[8] = {p0.x, p0.y, p0.z, p0.w, p1.x, p1.y, p1.z, p1.w};
            bf16x8 ahi, alo;
#pragma unroll
            for (int j = 0; j < 8; ++j) {
                __bf16 h = (__bf16)av[j];
                ahi[j] = h;
                alo[j] = (__bf16)(av[j] - (float)h);
            }
            const bf16x8* Whi = Wfrag + (size_t)((layer * 2 + 0) * 4 + kt) * 8 * 64;
            const bf16x8* Wlo = Wfrag + (size_t)((layer * 2 + 1) * 4 + kt) * 8 * 64;
#pragma unroll
            for (int ct = 0; ct < 8; ++ct) {
                bf16x8 bhi = Whi[ct * 64 + lane];
                bf16x8 blo = Wlo[ct * 64 + lane];
                acc[ct] = __builtin_amdgcn_mfma_f32_16x16x32_bf16(alo, bhi, acc[ct], 0, 0, 0);
                acc[ct] = __builtin_amdgcn_mfma_f32_16x16x32_bf16(ahi, blo, acc[ct], 0, 0, 0);
                acc[ct] = __builtin_amdgcn_mfma_f32_16x16x32_bf16(ahi, bhi, acc[ct], 0, 0, 0);
            }
        }
        // epilogue: C/D map col=lane&15, row=(lane>>4)*4+r
        if (layer < 2) {
            __syncthreads();  // staging/readers done before overwrite (cheap, 2 total)
#pragma unroll
            for (int ct = 0; ct < 8; ++ct) {
                float bv = bias[layer][ct * 16 + mrow];
#pragma unroll
                for (int r = 0; r < 4; ++r)
                    HS[wv * 16 + kg * 4 + r][ct * 16 + mrow] =
                        fmaxf(acc[ct][r] + bv, 0.f);
            }
            __syncthreads();
        } else {
#pragma unroll
            for (int ct = 0; ct < 8; ++ct) {
                float bv = b2[ct * 16 + mrow];
#pragma unroll
                for (int r = 0; r < 4; ++r) {
                    int grow = row0 + wv * 16 + kg * 4 + r;
                    if (grow < n)
                        C[(size_t)grow * 128 + ct * 16 + mrow] = acc[ct][r] + bv;
                }
            }
        }
    }
}

extern "C" void kernel_launch(void* const* d_in, const int* in_sizes, int n_in,
                              void* d_out, int out_size, void* d_ws, size_t ws_size,
                              hipStream_t stream) {
    const float* x  = (const float*)d_in[0];
    const int*  src = (const int*)d_in[1];
    const int*  dst = (const int*)d_in[2];
    const float* Wc = (const float*)d_in[3];
    const float* bc = (const float*)d_in[4];
    const float* W1 = (const float*)d_in[5];
    const float* b1 = (const float*)d_in[6];
    const float* W2 = (const float*)d_in[7];
    const float* b2 = (const float*)d_in[8];
    float* out = (float*)d_out;

    char* ws = (char*)d_ws;
    __bf16* Wf   = (__bf16*)ws;                      // 98304 bf16 = 196608 B (16B aligned)
    int*   degO  = (int*)(ws + 196608);              // NN
    int*   degI    = degO + NN;                      // NN
    int*   cursor  = degI + NN;                      // NN
    int*   rowptr  = cursor + NN;                    // NN+1
    float* normO   = (float*)(rowptr + NN + 1);      // NN
    float* normI   = normO + NN;                     // NN
    int*   bsum    = (int*)(normI + NN);             // NB
    int*   boff    = bsum + NB;                      // NB
    int*   csr_src = boff + NB;                      // NE

    hipMemsetAsync(degO, 0, (size_t)3 * NN * sizeof(int), stream);

    wprep_kernel<<<24, 256, 0, stream>>>(Wc, W1, W2, Wf);
    deg_kernel<<<(NE + 255) / 256, 256, 0, stream>>>(src, dst, degO, degI, NE);
    psum_kernel<<<NB, 256, 0, stream>>>(degI, bsum);
    pscan_kernel<<<1, 512, 0, stream>>>(bsum, boff);
    pfinal_kernel<<<NB, 256, 0, stream>>>(degI, boff, rowptr);
    norm_kernel<<<(NN + 255) / 256, 256, 0, stream>>>(degO, degI, normO, normI, NN);
    scatter_kernel<<<(NE + 255) / 256, 256, 0, stream>>>(src, dst, rowptr, cursor, csr_src, NE);

    // agg (both norms folded) -> d_out
    gather_kernel<<<(NN + 7) / 8, 256, 0, stream>>>(x, rowptr, csr_src, normO, normI, out);

    // fused 3-layer MLP via MFMA, in-place on d_out
    mlp_mfma<<<(NN + 63) / 64, 256, 0, stream>>>(out, Wf, bc, b1, b2, out, NN);
}

// Round 5
// 384.249 us; speedup vs baseline: 7.7899x; 1.1632x over previous
//
#include <hip/hip_runtime.h>

#define NN 100000
#define NE 1600000
#define NB 391  // ceil(NN/256)

typedef __attribute__((ext_vector_type(8))) __bf16 bf16x8;
typedef __attribute__((ext_vector_type(4))) float f32x4;

// ---------------- degree count + dst ticket capture -----------------------
__global__ __launch_bounds__(256) void deg_kernel(const int* __restrict__ src,
                                                  const int* __restrict__ dst,
                                                  int* __restrict__ degO,
                                                  int* __restrict__ degI,
                                                  int* __restrict__ ticket, int E) {
    int e = blockIdx.x * 256 + threadIdx.x;
    if (e < E) {
        atomicAdd(&degO[src[e]], 1);
        ticket[e] = atomicAdd(&degI[dst[e]], 1);
    }
}

// ---------------- scan phase 1: per-block sums ----------------------------
__global__ __launch_bounds__(256) void psum_kernel(const int* __restrict__ deg,
                                                   int* __restrict__ bsum) {
    int t = threadIdx.x;
    int i = blockIdx.x * 256 + t;
    __shared__ int sm[256];
    sm[t] = (i < NN) ? deg[i] : 0;
    __syncthreads();
    for (int o = 128; o; o >>= 1) {
        if (t < o) sm[t] += sm[t + o];
        __syncthreads();
    }
    if (t == 0) bsum[blockIdx.x] = sm[0];
}

// ---------------- scan phase 2: exclusive scan of NB partials -------------
__global__ __launch_bounds__(512) void pscan_kernel(const int* __restrict__ bsum,
                                                    int* __restrict__ boff) {
    __shared__ int sm[512];
    int t = threadIdx.x;
    int v = (t < NB) ? bsum[t] : 0;
    sm[t] = v;
    __syncthreads();
    for (int o = 1; o < 512; o <<= 1) {
        int u = (t >= o) ? sm[t - o] : 0;
        __syncthreads();
        sm[t] += u;
        __syncthreads();
    }
    if (t < NB) boff[t] = sm[t] - v;
}

// ---------------- scan phase 3: local scan + offset -> rowptr -------------
__global__ __launch_bounds__(256) void pfinal_kernel(const int* __restrict__ deg,
                                                     const int* __restrict__ boff,
                                                     int* __restrict__ rowptr) {
    int t = threadIdx.x;
    int i = blockIdx.x * 256 + t;
    int v = (i < NN) ? deg[i] : 0;
    __shared__ int sm[256];
    sm[t] = v;
    __syncthreads();
    for (int o = 1; o < 256; o <<= 1) {
        int u = (t >= o) ? sm[t - o] : 0;
        __syncthreads();
        sm[t] += u;
        __syncthreads();
    }
    if (i < NN) {
        int base = boff[blockIdx.x];
        int incl = base + sm[t];
        rowptr[i] = incl - v;
        if (i == NN - 1) rowptr[NN] = incl;
    }
}

// ---------------- norms from integer degrees ------------------------------
__global__ __launch_bounds__(256) void norm_kernel(const int* __restrict__ degO,
                                                   const int* __restrict__ degI,
                                                   float* __restrict__ normO,
                                                   float* __restrict__ normI, int n) {
    int i = blockIdx.x * 256 + threadIdx.x;
    if (i < n) {
        normO[i] = rsqrtf(fmaxf((float)degO[i], 1.0f));
        normI[i] = rsqrtf(fmaxf((float)degI[i], 1.0f));
    }
}

// ---------------- scatter edges into CSR buckets (no atomics) -------------
__global__ __launch_bounds__(256) void scatter_kernel(const int* __restrict__ src,
                                                      const int* __restrict__ dst,
                                                      const int* __restrict__ rowptr,
                                                      const int* __restrict__ ticket,
                                                      int* __restrict__ csr_src, int E) {
    int e = blockIdx.x * 256 + threadIdx.x;
    if (e < E) {
        int d = dst[e];
        csr_src[rowptr[d] + ticket[e]] = src[e];
    }
}

// ---------------- gather: agg[v] = normI[v] * sum_{u in N(v)} x[u]*normO[u]
__global__ __launch_bounds__(256) void gather_kernel(const float* __restrict__ x,
                                                     const int* __restrict__ rowptr,
                                                     const int* __restrict__ csr_src,
                                                     const float* __restrict__ normO,
                                                     const float* __restrict__ normI,
                                                     float* __restrict__ agg) {
    int node = blockIdx.x * 8 + (threadIdx.x >> 5);
    int lane = threadIdx.x & 31;
    if (node >= NN) return;
    int beg = rowptr[node], end = rowptr[node + 1];
    float ax = 0.f, ay = 0.f, az = 0.f, aw = 0.f;
    int j = beg;
    for (; j + 4 <= end; j += 4) {
        int s0 = csr_src[j], s1 = csr_src[j + 1], s2 = csr_src[j + 2], s3 = csr_src[j + 3];
        float n0 = normO[s0], n1 = normO[s1], n2 = normO[s2], n3 = normO[s3];
        float4 v0 = *reinterpret_cast<const float4*>(&x[(size_t)s0 * 128 + lane * 4]);
        float4 v1 = *reinterpret_cast<const float4*>(&x[(size_t)s1 * 128 + lane * 4]);
        float4 v2 = *reinterpret_cast<const float4*>(&x[(size_t)s2 * 128 + lane * 4]);
        float4 v3 = *reinterpret_cast<const float4*>(&x[(size_t)s3 * 128 + lane * 4]);
        ax = fmaf(v0.x, n0, ax); ay = fmaf(v0.y, n0, ay); az = fmaf(v0.z, n0, az); aw = fmaf(v0.w, n0, aw);
        ax = fmaf(v1.x, n1, ax); ay = fmaf(v1.y, n1, ay); az = fmaf(v1.z, n1, az); aw = fmaf(v1.w, n1, aw);
        ax = fmaf(v2.x, n2, ax); ay = fmaf(v2.y, n2, ay); az = fmaf(v2.z, n2, az); aw = fmaf(v2.w, n2, aw);
        ax = fmaf(v3.x, n3, ax); ay = fmaf(v3.y, n3, ay); az = fmaf(v3.z, n3, az); aw = fmaf(v3.w, n3, aw);
    }
    for (; j < end; ++j) {
        int s = csr_src[j];
        float ns = normO[s];
        float4 v = *reinterpret_cast<const float4*>(&x[(size_t)s * 128 + lane * 4]);
        ax = fmaf(v.x, ns, ax);
        ay = fmaf(v.y, ns, ay);
        az = fmaf(v.z, ns, az);
        aw = fmaf(v.w, ns, aw);
    }
    float ni = normI[node];
    float4 o = make_float4(ax * ni, ay * ni, az * ni, aw * ni);
    *reinterpret_cast<float4*>(&agg[(size_t)node * 128 + lane * 4]) = o;
}

// ---------------- W prep: pack Wc/W1/W2 into hi/lo bf16 B-fragments -------
__global__ __launch_bounds__(256) void wprep_kernel(const float* __restrict__ Wc,
                                                    const float* __restrict__ W1,
                                                    const float* __restrict__ W2,
                                                    __bf16* __restrict__ Wf) {
    int t = blockIdx.x * 256 + threadIdx.x;
    if (t >= 3 * 4 * 8 * 64) return;
    int lane = t & 63;
    int ct = (t >> 6) & 7;
    int kt = (t >> 9) & 3;
    int layer = t >> 11;
    const float* W = (layer == 0) ? Wc : (layer == 1) ? W1 : W2;
    int c = ct * 16 + (lane & 15);
    int kbase = kt * 32 + (lane >> 4) * 8;
    bf16x8 hi, lo;
#pragma unroll
    for (int j = 0; j < 8; ++j) {
        float wv = W[(size_t)(kbase + j) * 128 + c];
        __bf16 h = (__bf16)wv;
        hi[j] = h;
        lo[j] = (__bf16)(wv - (float)h);
    }
    bf16x8* Wv = reinterpret_cast<bf16x8*>(Wf);
    Wv[((size_t)((layer * 2 + 0) * 4 + kt) * 8 + ct) * 64 + lane] = hi;
    Wv[((size_t)((layer * 2 + 1) * 4 + kt) * 8 + ct) * 64 + lane] = lo;
}

// ---------------- fused 3-layer MLP via split-bf16 MFMA -------------------
__global__ __launch_bounds__(256) void mlp_mfma(const float* __restrict__ A,
                                                const __bf16* __restrict__ Wf,
                                                const float* __restrict__ bc,
                                                const float* __restrict__ b1,
                                                const float* __restrict__ b2,
                                                float* __restrict__ C, int n) {
    __shared__ float HS[64][132];
    const int tid = threadIdx.x;
    const int lane = tid & 63;
    const int wv = tid >> 6;
    const int row0 = blockIdx.x * 64;
    const int mrow = lane & 15;
    const int kg = lane >> 4;

    {
        int r = tid >> 5;
        int c4 = (tid & 31) * 4;
#pragma unroll
        for (int i = 0; i < 8; ++i) {
            int row = i * 8 + r;
            int grow = row0 + row;
            float4 v = make_float4(0.f, 0.f, 0.f, 0.f);
            if (grow < n)
                v = *reinterpret_cast<const float4*>(&A[(size_t)grow * 128 + c4]);
            *reinterpret_cast<float4*>(&HS[row][c4]) = v;
        }
    }
    __syncthreads();

    const bf16x8* Wfrag = reinterpret_cast<const bf16x8*>(Wf);
    const float* bias[3] = {bc, b1, b2};

#pragma unroll
    for (int layer = 0; layer < 3; ++layer) {
        f32x4 acc[8] = {};
#pragma unroll
        for (int kt = 0; kt < 4; ++kt) {
            const float* hsrc = &HS[wv * 16 + mrow][kt * 32 + kg * 8];
            float4 p0 = *reinterpret_cast<const float4*>(hsrc);
            float4 p1 = *reinterpret_cast<const float4*>(hsrc + 4);
            float av[8] = {p0.x, p0.y, p0.z, p0.w, p1.x, p1.y, p1.z, p1.w};
            bf16x8 ahi, alo;
#pragma unroll
            for (int j = 0; j < 8; ++j) {
                __bf16 h = (__bf16)av[j];
                ahi[j] = h;
                alo[j] = (__bf16)(av[j] - (float)h);
            }
            const bf16x8* Whi = Wfrag + (size_t)((layer * 2 + 0) * 4 + kt) * 8 * 64;
            const bf16x8* Wlo = Wfrag + (size_t)((layer * 2 + 1) * 4 + kt) * 8 * 64;
#pragma unroll
            for (int ct = 0; ct < 8; ++ct) {
                bf16x8 bhi = Whi[ct * 64 + lane];
                bf16x8 blo = Wlo[ct * 64 + lane];
                acc[ct] = __builtin_amdgcn_mfma_f32_16x16x32_bf16(alo, bhi, acc[ct], 0, 0, 0);
                acc[ct] = __builtin_amdgcn_mfma_f32_16x16x32_bf16(ahi, blo, acc[ct], 0, 0, 0);
                acc[ct] = __builtin_amdgcn_mfma_f32_16x16x32_bf16(ahi, bhi, acc[ct], 0, 0, 0);
            }
        }
        if (layer < 2) {
            __syncthreads();
#pragma unroll
            for (int ct = 0; ct < 8; ++ct) {
                float bv = bias[layer][ct * 16 + mrow];
#pragma unroll
                for (int r = 0; r < 4; ++r)
                    HS[wv * 16 + kg * 4 + r][ct * 16 + mrow] =
                        fmaxf(acc[ct][r] + bv, 0.f);
            }
            __syncthreads();
        } else {
#pragma unroll
            for (int ct = 0; ct < 8; ++ct) {
                float bv = b2[ct * 16 + mrow];
#pragma unroll
                for (int r = 0; r < 4; ++r) {
                    int grow = row0 + wv * 16 + kg * 4 + r;
                    if (grow < n)
                        C[(size_t)grow * 128 + ct * 16 + mrow] = acc[ct][r] + bv;
                }
            }
        }
    }
}

extern "C" void kernel_launch(void* const* d_in, const int* in_sizes, int n_in,
                              void* d_out, int out_size, void* d_ws, size_t ws_size,
                              hipStream_t stream) {
    const float* x  = (const float*)d_in[0];
    const int*  src = (const int*)d_in[1];
    const int*  dst = (const int*)d_in[2];
    const float* Wc = (const float*)d_in[3];
    const float* bc = (const float*)d_in[4];
    const float* W1 = (const float*)d_in[5];
    const float* b1 = (const float*)d_in[6];
    const float* W2 = (const float*)d_in[7];
    const float* b2 = (const float*)d_in[8];
    float* out = (float*)d_out;

    char* ws = (char*)d_ws;
    __bf16* Wf   = (__bf16*)ws;                      // 196608 B
    int*   degO  = (int*)(ws + 196608);              // NN
    int*   degI    = degO + NN;                      // NN
    int*   rowptr  = degI + NN;                      // NN+1
    float* normO   = (float*)(rowptr + NN + 1);      // NN
    float* normI   = normO + NN;                     // NN
    int*   bsum    = (int*)(normI + NN);             // NB
    int*   boff    = bsum + NB;                      // NB
    int*   ticket  = boff + NB;                      // NE
    int*   csr_src = ticket + NE;                    // NE

    // zero degO, degI (contiguous 2*NN ints)
    hipMemsetAsync(degO, 0, (size_t)2 * NN * sizeof(int), stream);

    wprep_kernel<<<24, 256, 0, stream>>>(Wc, W1, W2, Wf);
    deg_kernel<<<(NE + 255) / 256, 256, 0, stream>>>(src, dst, degO, degI, ticket, NE);
    psum_kernel<<<NB, 256, 0, stream>>>(degI, bsum);
    pscan_kernel<<<1, 512, 0, stream>>>(bsum, boff);
    pfinal_kernel<<<NB, 256, 0, stream>>>(degI, boff, rowptr);
    norm_kernel<<<(NN + 255) / 256, 256, 0, stream>>>(degO, degI, normO, normI, NN);
    scatter_kernel<<<(NE + 255) / 256, 256, 0, stream>>>(src, dst, rowptr, ticket, csr_src, NE);

    // agg (both norms folded) -> d_out
    gather_kernel<<<(NN + 7) / 8, 256, 0, stream>>>(x, rowptr, csr_src, normO, normI, out);

    // fused 3-layer MLP via MFMA, in-place on d_out
    mlp_mfma<<<(NN + 63) / 64, 256, 0, stream>>>(out, Wf, bc, b1, b2, out, NN);
}